// Round 1
// baseline (337.267 us; speedup 1.0000x reference)
//
#include <hip/hip_runtime.h>

// CRF forward (log-partition minus gold score), B=2048, L=512, T=32.
// One batch per WAVE (lanes 32-63 replicate lanes 0-31), 2048 waves ->
// 2 waves/SIMD. Alpha broadcast is done with v_readlane -> SGPRs instead of
// an LDS write/read round-trip: the per-step critical path is now pure VALU
// (32 readlanes + 32 v_fma with SGPR first operand). Zero LDS ops on the
// recurrence chain; renorm scalar comes from readfirstlane (batch is
// wave-uniform). Scaled linear-space forward:
//   a[j] <- (sum_i a[i]*E[i][j]) * exp(emit[t][j]),  E = exp(trans)

constexpr int TT = 32;   // tags
constexpr int LL = 512;  // seq len

#define L2E  1.4426950408889634f
#define LN2f 0.6931471805599453f

template<int X>
__device__ __forceinline__ float swzxf(float v) {
  // lane ^ X within each 32-lane group (BitMode: and=0x1F, xor=X)
  return __int_as_float(__builtin_amdgcn_ds_swizzle(__float_as_int(v), (X << 10) | 0x1F));
}

__device__ __forceinline__ float rdlanef(float v, int k) {
  // after unrolling, k is a literal -> v_readlane_b32 s, v, k
  return __int_as_float(__builtin_amdgcn_readlane(__float_as_int(v), k));
}

__global__ __launch_bounds__(64) void crf_fwd(
    const float* __restrict__ emit, const float* __restrict__ trans,
    const int* __restrict__ tags, const int* __restrict__ lengths,
    float* __restrict__ out, int B)
{
  __shared__ float s_trans[TT * TT];
  {
    // 64 threads x 4 float4 = 1024 floats
    const float4* t4 = (const float4*)trans;
    float4* st4 = (float4*)s_trans;
#pragma unroll
    for (int k = 0; k < 4; ++k)
      st4[threadIdx.x + 64 * k] = t4[threadIdx.x + 64 * k];
  }
  __syncthreads();

  const int j = threadIdx.x & 31;   // tag index; both halves identical
  const int b = blockIdx.x;         // one batch per wave
  if (b >= B) return;

  // E columns in registers: Ec[i] = exp(trans[i][j])
  float Ec[TT];
#pragma unroll
  for (int i = 0; i < TT; ++i)
    Ec[i] = __builtin_amdgcn_exp2f(s_trans[i * TT + j] * L2E);

  const int len = lengths[b];       // wave-uniform
  const float* erow = emit + (size_t)b * (LL * TT);
  const int*  trow  = tags + (size_t)b * LL;

  // t = 0 prologue
  float e0   = erow[j];
  int   ptag = trow[0];
  float a    = __builtin_amdgcn_exp2f(e0 * L2E);  // alpha, linear space
  float gacc = (j == ptag) ? e0 : 0.f;            // per-lane gold accumulator
  float LS   = 0.f;                               // accumulated log2 scale

  const int nch = (len - 1 + 3) >> 2;   // 4-step chunks (uniform)

  // software pipeline: current chunk (eb/tg), next (en/tgn), prefetch 2 ahead
  float eb[4], en[4];
  int   tg[4], tgn[4];
#pragma unroll
  for (int k = 0; k < 4; ++k) {
    int t = 1 + k; int tc = t < LL ? t : LL - 1;
    eb[k] = erow[tc * TT + j];
    tg[k] = trow[tc];
  }
#pragma unroll
  for (int k = 0; k < 4; ++k) {
    int t = 5 + k; int tc = t < LL ? t : LL - 1;
    en[k] = erow[tc * TT + j];
    tgn[k] = trow[tc];
  }

  for (int c = 0; c < nch; ++c) {
    const int tb = 1 + (c << 2);

    // prefetch chunk c+2 (clamped)
    float ep[4]; int tgp[4];
#pragma unroll
    for (int k = 0; k < 4; ++k) {
      int t = tb + 8 + k; int tc = t < LL ? t : LL - 1;
      ep[k]  = erow[tc * TT + j];
      tgp[k] = trow[tc];
    }

    // exp(emit) for the whole chunk up front (off critical path)
    float e2v[4];
#pragma unroll
    for (int k = 0; k < 4; ++k) e2v[k] = __builtin_amdgcn_exp2f(eb[k] * L2E);

#pragma unroll
    for (int k = 0; k < 4; ++k) {
      const int t = tb + k;

      // alpha broadcast via readlane -> SGPRs; dot = v_fma with SGPR src0.
      // No LDS on the critical path.
      float acc0 = 0.f, acc1 = 0.f, acc2 = 0.f, acc3 = 0.f;
#pragma unroll
      for (int q = 0; q < 8; ++q) {
        acc0 = fmaf(rdlanef(a, 4 * q + 0), Ec[4 * q + 0], acc0);
        acc1 = fmaf(rdlanef(a, 4 * q + 1), Ec[4 * q + 1], acc1);
        acc2 = fmaf(rdlanef(a, 4 * q + 2), Ec[4 * q + 2], acc2);
        acc3 = fmaf(rdlanef(a, 4 * q + 3), Ec[4 * q + 3], acc3);
      }
      float anew = ((acc0 + acc1) + (acc2 + acc3)) * e2v[k];
      const bool valid = t < len;   // wave-uniform
      a = valid ? anew : a;

      // gold: lane==tag accumulates emit[t][tag] + trans[ptag][tag]
      // (same-address broadcast read across both halves; off critical path)
      int tag  = tg[k];
      float tr = s_trans[(ptag << 5) + j];
      gacc += ((j == tag) && valid) ? (eb[k] + tr) : 0.f;
      ptag = tag;
    }

    // cheap renorm: scale by lane-0 alpha (logz-invariant, safe when masked).
    // Batch is wave-uniform now -> readfirstlane, no ds_swizzle.
    float m = fmaxf(__int_as_float(__builtin_amdgcn_readfirstlane(__float_as_int(a))), 1e-30f);
    float r = __builtin_amdgcn_rcpf(m);
    a *= r;
    LS += __builtin_amdgcn_logf(m);   // v_log_f32 = log2

    // rotate pipeline buffers
#pragma unroll
    for (int k = 0; k < 4; ++k) {
      eb[k] = en[k]; tg[k] = tgn[k];
      en[k] = ep[k]; tgn[k] = tgp[k];
    }
  }

  // reduce alpha-sum and gold-sum across the lower 32-lane group
  // (upper half holds replicated alpha / garbage gold; group-0 swizzles only)
  float s  = a;
  float gs = gacc;
  s += swzxf<1>(s);   gs += swzxf<1>(gs);
  s += swzxf<2>(s);   gs += swzxf<2>(gs);
  s += swzxf<4>(s);   gs += swzxf<4>(gs);
  s += swzxf<8>(s);   gs += swzxf<8>(gs);
  s += swzxf<16>(s);  gs += swzxf<16>(gs);

  float logz = (__builtin_amdgcn_logf(s) + LS) * LN2f;
  if (threadIdx.x == 0) out[b] = logz - gs;
}

extern "C" void kernel_launch(void* const* d_in, const int* in_sizes, int n_in,
                              void* d_out, int out_size, void* d_ws, size_t ws_size,
                              hipStream_t stream) {
  const float* emit    = (const float*)d_in[0];
  const float* trans   = (const float*)d_in[1];
  const int*   tags    = (const int*)d_in[2];
  const int*   lengths = (const int*)d_in[3];
  float*       out     = (float*)d_out;
  const int B = in_sizes[3];             // lengths is (B,)
  hipLaunchKernelGGL(crf_fwd, dim3(B), dim3(64), 0, stream,
                     emit, trans, tags, lengths, out, B);
}

// Round 2
// 296.978 us; speedup vs baseline: 1.1357x; 1.1357x over previous
//
#include <hip/hip_runtime.h>

// CRF forward (log-partition minus gold score), B=2048, L=512, T=32.
// One batch per WAVE, 2048 waves -> exactly 2 waves/SIMD.
// __launch_bounds__(64, 2): tell the allocator we only ever need 2 waves/EU,
// so Ec[32] + pipeline buffers stay in VGPRs (R1 showed VGPR_Count=32 ->
// compiler rematerialized Ec from LDS+exp inside the loop: 885 cy/step).
// Alpha broadcast via v_readlane -> SGPR, dot = v_fma with SGPR src.
// Hot loop is mask-free (full 4-step chunks only); masked tail separate.
// Gold trans LDS reads prefetched per-chunk (addresses independent of the
// alpha chain). Scaled linear-space forward:
//   a[j] <- (sum_i a[i]*E[i][j]) * exp(emit[t][j]),  E = exp(trans)

constexpr int TT = 32;   // tags
constexpr int LL = 512;  // seq len

#define L2E  1.4426950408889634f
#define LN2f 0.6931471805599453f

template<int X>
__device__ __forceinline__ float swzxf(float v) {
  // lane ^ X within each 32-lane group (BitMode: and=0x1F, xor=X)
  return __int_as_float(__builtin_amdgcn_ds_swizzle(__float_as_int(v), (X << 10) | 0x1F));
}

__device__ __forceinline__ float rdlanef(float v, int k) {
  // after unrolling, k is a literal -> v_readlane_b32 s, v, k
  return __int_as_float(__builtin_amdgcn_readlane(__float_as_int(v), k));
}

__global__ __launch_bounds__(64, 2) void crf_fwd(
    const float* __restrict__ emit, const float* __restrict__ trans,
    const int* __restrict__ tags, const int* __restrict__ lengths,
    float* __restrict__ out, int B)
{
  __shared__ float s_trans[TT * TT];
  {
    // 64 threads x 4 float4 = 1024 floats
    const float4* t4 = (const float4*)trans;
    float4* st4 = (float4*)s_trans;
#pragma unroll
    for (int k = 0; k < 4; ++k)
      st4[threadIdx.x + 64 * k] = t4[threadIdx.x + 64 * k];
  }
  __syncthreads();

  const int j = threadIdx.x & 31;   // tag index; both wave halves identical
  const int b = blockIdx.x;         // one batch per wave
  if (b >= B) return;

  // E columns in registers: Ec[i] = exp(trans[i][j]).
  float Ec[TT];
#pragma unroll
  for (int i = 0; i < TT; ++i)
    Ec[i] = __builtin_amdgcn_exp2f(s_trans[i * TT + j] * L2E);
  // Pin Ec in VGPRs: opaque asm prevents rematerialization from LDS.
#pragma unroll
  for (int i = 0; i < TT; ++i) asm volatile("" : "+v"(Ec[i]));

  const int len = lengths[b];       // wave-uniform
  const float* erow = emit + (size_t)b * (LL * TT);
  const int*  trow  = tags + (size_t)b * LL;

  // t = 0 prologue
  float e0   = erow[j];
  int   ptag = trow[0];
  float a    = __builtin_amdgcn_exp2f(e0 * L2E);  // alpha, linear space
  float gacc = (j == ptag) ? e0 : 0.f;            // per-lane gold accumulator
  float LS   = 0.f;                               // accumulated log2 scale

  const int nfull = (len - 1) >> 2;   // full (unmasked) 4-step chunks
  const int rem   = (len - 1) & 3;    // masked tail steps

  // software pipeline: current chunk (eb/tg), next (en/tgn), prefetch 2 ahead
  float eb[4], en[4];
  int   tg[4], tgn[4];
#pragma unroll
  for (int k = 0; k < 4; ++k) {
    int t = 1 + k; int tc = t < LL ? t : LL - 1;
    eb[k] = erow[tc * TT + j];
    tg[k] = trow[tc];
  }
#pragma unroll
  for (int k = 0; k < 4; ++k) {
    int t = 5 + k; int tc = t < LL ? t : LL - 1;
    en[k] = erow[tc * TT + j];
    tgn[k] = trow[tc];
  }

  for (int c = 0; c < nfull; ++c) {
    const int tb = 1 + (c << 2);

    // prefetch chunk c+2 (clamped)
    float ep[4]; int tgp[4];
#pragma unroll
    for (int k = 0; k < 4; ++k) {
      int t = tb + 8 + k; int tc = t < LL ? t : LL - 1;
      ep[k]  = erow[tc * TT + j];
      tgp[k] = trow[tc];
    }

    // gold-transition LDS reads for the whole chunk, issued up front:
    // ptag chain = [ptag, tg[0], tg[1], tg[2]] -- all known at chunk start,
    // independent of the alpha recurrence.
    float trv[4];
    trv[0] = s_trans[(ptag  << 5) + j];
    trv[1] = s_trans[(tg[0] << 5) + j];
    trv[2] = s_trans[(tg[1] << 5) + j];
    trv[3] = s_trans[(tg[2] << 5) + j];

    // exp(emit) for the whole chunk up front (off critical path)
    float e2v[4];
#pragma unroll
    for (int k = 0; k < 4; ++k) e2v[k] = __builtin_amdgcn_exp2f(eb[k] * L2E);

#pragma unroll
    for (int k = 0; k < 4; ++k) {
      // alpha broadcast via readlane -> SGPRs; dot = v_fma with SGPR src.
      float acc0 = 0.f, acc1 = 0.f, acc2 = 0.f, acc3 = 0.f;
#pragma unroll
      for (int q = 0; q < 8; ++q) {
        acc0 = fmaf(rdlanef(a, 4 * q + 0), Ec[4 * q + 0], acc0);
        acc1 = fmaf(rdlanef(a, 4 * q + 1), Ec[4 * q + 1], acc1);
        acc2 = fmaf(rdlanef(a, 4 * q + 2), Ec[4 * q + 2], acc2);
        acc3 = fmaf(rdlanef(a, 4 * q + 3), Ec[4 * q + 3], acc3);
      }
      a = ((acc0 + acc1) + (acc2 + acc3)) * e2v[k];   // no mask: chunk is full

      // gold: lane==tag accumulates emit[t][tag] + trans[ptag][tag]
      gacc += (j == tg[k]) ? (eb[k] + trv[k]) : 0.f;
    }
    ptag = tg[3];

    // cheap renorm: scale by lane-0 alpha (logz-invariant, safe when masked).
    float m = fmaxf(__int_as_float(__builtin_amdgcn_readfirstlane(__float_as_int(a))), 1e-30f);
    float r = __builtin_amdgcn_rcpf(m);
    a *= r;
    LS += __builtin_amdgcn_logf(m);   // v_log_f32 = log2

    // rotate pipeline buffers
#pragma unroll
    for (int k = 0; k < 4; ++k) {
      eb[k] = en[k]; tg[k] = tgn[k];
      en[k] = ep[k]; tgn[k] = tgp[k];
    }
  }

  // masked tail: rem in {0,1,2,3} steps, data already in eb/tg (chunk nfull)
#pragma unroll
  for (int k = 0; k < 3; ++k) {
    if (k < rem) {                       // wave-uniform branch
      float e2 = __builtin_amdgcn_exp2f(eb[k] * L2E);
      float acc0 = 0.f, acc1 = 0.f, acc2 = 0.f, acc3 = 0.f;
#pragma unroll
      for (int q = 0; q < 8; ++q) {
        acc0 = fmaf(rdlanef(a, 4 * q + 0), Ec[4 * q + 0], acc0);
        acc1 = fmaf(rdlanef(a, 4 * q + 1), Ec[4 * q + 1], acc1);
        acc2 = fmaf(rdlanef(a, 4 * q + 2), Ec[4 * q + 2], acc2);
        acc3 = fmaf(rdlanef(a, 4 * q + 3), Ec[4 * q + 3], acc3);
      }
      a = ((acc0 + acc1) + (acc2 + acc3)) * e2;
      float tr = s_trans[(ptag << 5) + j];
      gacc += (j == tg[k]) ? (eb[k] + tr) : 0.f;
      ptag = tg[k];
    }
  }

  // reduce alpha-sum and gold-sum across the 32-lane group
  float s  = a;
  float gs = gacc;
  s += swzxf<1>(s);   gs += swzxf<1>(gs);
  s += swzxf<2>(s);   gs += swzxf<2>(gs);
  s += swzxf<4>(s);   gs += swzxf<4>(gs);
  s += swzxf<8>(s);   gs += swzxf<8>(gs);
  s += swzxf<16>(s);  gs += swzxf<16>(gs);

  float logz = (__builtin_amdgcn_logf(s) + LS) * LN2f;
  if (threadIdx.x == 0) out[b] = logz - gs;
}

extern "C" void kernel_launch(void* const* d_in, const int* in_sizes, int n_in,
                              void* d_out, int out_size, void* d_ws, size_t ws_size,
                              hipStream_t stream) {
  const float* emit    = (const float*)d_in[0];
  const float* trans   = (const float*)d_in[1];
  const int*   tags    = (const int*)d_in[2];
  const int*   lengths = (const int*)d_in[3];
  float*       out     = (float*)d_out;
  const int B = in_sizes[3];             // lengths is (B,)
  hipLaunchKernelGGL(crf_fwd, dim3(B), dim3(64), 0, stream,
                     emit, trans, tags, lengths, out, B);
}

// Round 3
// 292.642 us; speedup vs baseline: 1.1525x; 1.0148x over previous
//
#include <hip/hip_runtime.h>

// CRF forward (log-partition minus gold score), B=2048, L=512, T=32.
// One batch per WAVE, 2048 waves -> 2/SIMD. R2 was stall-bound (VALUBusy 36%,
// ~694 cy/step wall vs ~165 cy issued). Suspected stalls: (a) tags read as
// wave-uniform -> s_load; SMEM+DS share lgkmcnt and SMEM retires OOO, so trv
// ds_read waits become lgkmcnt(0) and drain next-chunk tag loads every chunk;
// (b) short (4-step) chunks expose vmcnt waits. R3: tags loaded as per-lane
// VECTOR loads (1 global_load_dword per 8-step chunk, lane k = tag[tb+k]),
// extracted with v_readlane (literal idx) -> zero SMEM in loop; 8-step
// register-double-buffered chunks, buffer choice by 2x loop unroll.
// Scaled linear-space forward:
//   a[j] <- (sum_i a[i]*E[i][j]) * exp(emit[t][j]),  E = exp(trans)

constexpr int TT = 32;   // tags
constexpr int LL = 512;  // seq len

#define L2E  1.4426950408889634f
#define LN2f 0.6931471805599453f

template<int X>
__device__ __forceinline__ float swzxf(float v) {
  // lane ^ X within each 32-lane group (BitMode: and=0x1F, xor=X)
  return __int_as_float(__builtin_amdgcn_ds_swizzle(__float_as_int(v), (X << 10) | 0x1F));
}
__device__ __forceinline__ float rdlf(float v, int k) {
  // literal k after unroll -> v_readlane_b32 s, v, k
  return __int_as_float(__builtin_amdgcn_readlane(__float_as_int(v), k));
}

__global__ __launch_bounds__(64, 2) void crf_fwd(
    const float* __restrict__ emit, const float* __restrict__ trans,
    const int* __restrict__ tags, const int* __restrict__ lengths,
    float* __restrict__ out, int B)
{
  __shared__ float s_trans[TT * TT];
  {
    const float4* t4 = (const float4*)trans;
    float4* st4 = (float4*)s_trans;
#pragma unroll
    for (int k = 0; k < 4; ++k)
      st4[threadIdx.x + 64 * k] = t4[threadIdx.x + 64 * k];
  }
  __syncthreads();

  const int j    = threadIdx.x & 31;  // tag index; both wave halves identical
  const int lane = threadIdx.x;       // 0..63, used for the tag vector load
  const int b    = blockIdx.x;        // one batch per wave
  if (b >= B) return;

  // E columns in registers: Ec[i] = exp(trans[i][j])
  float Ec[TT];
#pragma unroll
  for (int i = 0; i < TT; ++i)
    Ec[i] = __builtin_amdgcn_exp2f(s_trans[i * TT + j] * L2E);
#pragma unroll
  for (int i = 0; i < TT; ++i) asm volatile("" : "+v"(Ec[i]));

  const int len = lengths[b];         // wave-uniform (pre-loop SMEM ok)
  const float* erow = emit + (size_t)b * (LL * TT);
  const int*  trow  = tags + (size_t)b * LL;

  // t = 0 prologue
  float e0   = erow[j];
  int   ptag = trow[0];               // pre-loop scalar load ok
  float a    = __builtin_amdgcn_exp2f(e0 * L2E);
  float gacc = (j == ptag) ? e0 : 0.f;
  float LS   = 0.f;

  const int nf = (len - 1) >> 3;      // full 8-step chunks
  const int r  = (len - 1) & 7;       // tail steps

  // double-buffered: 8 emit floats + 1 tag-vector (lane k = tag[tb+k])
  float eA[8], eB[8];
  int tvA, tvB;
#pragma unroll
  for (int k = 0; k < 8; ++k) { int t = 1 + k; eA[k] = erow[t * TT + j]; }
  { int t = 1 + lane; t = t < LL ? t : LL - 1; tvA = trow[t]; }

  // one forward step: SGPR-broadcast dot (32 readlane + 32 fma), then scale
#define STEP(E2_) do {                                                     \
    float acc0 = 0.f, acc1 = 0.f, acc2 = 0.f, acc3 = 0.f;                  \
    _Pragma("unroll")                                                      \
    for (int q = 0; q < 8; ++q) {                                          \
      acc0 = fmaf(rdlf(a, 4 * q + 0), Ec[4 * q + 0], acc0);                \
      acc1 = fmaf(rdlf(a, 4 * q + 1), Ec[4 * q + 1], acc1);                \
      acc2 = fmaf(rdlf(a, 4 * q + 2), Ec[4 * q + 2], acc2);                \
      acc3 = fmaf(rdlf(a, 4 * q + 3), Ec[4 * q + 3], acc3);                \
    }                                                                      \
    a = ((acc0 + acc1) + (acc2 + acc3)) * (E2_);                           \
  } while (0)

  // renorm by lane-0 alpha (logz-invariant); every 4 steps (overflow bound)
#define RENORM() do {                                                      \
    float mt = fmaxf(a, 1e-30f);                                           \
    float m  = __int_as_float(                                             \
        __builtin_amdgcn_readfirstlane(__float_as_int(mt)));               \
    a *= __builtin_amdgcn_rcpf(m);                                         \
    LS += __builtin_amdgcn_logf(m);                                        \
  } while (0)

  // one 8-step chunk: consume (EC,TVC), prefetch next into (EN,TVN)
#define CHUNK(EC, TVC, EN, TVN, TB) do {                                   \
    _Pragma("unroll")                                                      \
    for (int k = 0; k < 8; ++k) {                                          \
      int t = (TB) + 8 + k; t = t < LL ? t : LL - 1;                       \
      EN[k] = erow[t * TT + j];                                            \
    }                                                                      \
    { int t = (TB) + 8 + lane; t = t < LL ? t : LL - 1; TVN = trow[t]; }   \
    _Pragma("unroll")                                                      \
    for (int s = 0; s < 2; ++s) {                                          \
      const int k0 = 4 * s;                                                \
      int p0 = (s == 0) ? ptag : __builtin_amdgcn_readlane(TVC, 3);        \
      int s0 = __builtin_amdgcn_readlane(TVC, k0 + 0);                     \
      int s1 = __builtin_amdgcn_readlane(TVC, k0 + 1);                     \
      int s2 = __builtin_amdgcn_readlane(TVC, k0 + 2);                     \
      int s3 = __builtin_amdgcn_readlane(TVC, k0 + 3);                     \
      float trv0 = s_trans[(p0 << 5) + j];                                 \
      float trv1 = s_trans[(s0 << 5) + j];                                 \
      float trv2 = s_trans[(s1 << 5) + j];                                 \
      float trv3 = s_trans[(s2 << 5) + j];                                 \
      float f0 = __builtin_amdgcn_exp2f(EC[k0 + 0] * L2E);                 \
      float f1 = __builtin_amdgcn_exp2f(EC[k0 + 1] * L2E);                 \
      float f2 = __builtin_amdgcn_exp2f(EC[k0 + 2] * L2E);                 \
      float f3 = __builtin_amdgcn_exp2f(EC[k0 + 3] * L2E);                 \
      STEP(f0); gacc += (j == s0) ? (EC[k0 + 0] + trv0) : 0.f;             \
      STEP(f1); gacc += (j == s1) ? (EC[k0 + 1] + trv1) : 0.f;             \
      STEP(f2); gacc += (j == s2) ? (EC[k0 + 2] + trv2) : 0.f;             \
      STEP(f3); gacc += (j == s3) ? (EC[k0 + 3] + trv3) : 0.f;             \
      RENORM();                                                            \
    }                                                                      \
    ptag = __builtin_amdgcn_readlane(TVC, 7);                              \
  } while (0)

  int c = 0;
  for (; c + 2 <= nf; c += 2) {
    CHUNK(eA, tvA, eB, tvB, 1 + (c << 3));
    CHUNK(eB, tvB, eA, tvA, 1 + ((c + 1) << 3));
  }
  if (c < nf) {
    CHUNK(eA, tvA, eB, tvB, 1 + (c << 3));
    ++c;
  }

  // masked tail: r in 0..7 steps; data prefetched by the last chunk (or the
  // prologue when nf==0). Buffer parity: nf even -> A, odd -> B.
#define TAIL(EC, TVC) do {                                                 \
    _Pragma("unroll")                                                      \
    for (int k = 0; k < 7; ++k) {                                          \
      if (k < r) {  /* wave-uniform */                                     \
        int sg = __builtin_amdgcn_readlane(TVC, k);                        \
        float trv = s_trans[(ptag << 5) + j];                              \
        float f = __builtin_amdgcn_exp2f(EC[k] * L2E);                     \
        STEP(f);                                                           \
        gacc += (j == sg) ? (EC[k] + trv) : 0.f;                           \
        ptag = sg;                                                         \
        if (k == 3) RENORM();                                              \
      }                                                                    \
    }                                                                      \
  } while (0)

  if (nf & 1) TAIL(eB, tvB); else TAIL(eA, tvA);

  // reduce alpha-sum and gold-sum across the 32-lane group
  float s  = a;
  float gs = gacc;
  s += swzxf<1>(s);   gs += swzxf<1>(gs);
  s += swzxf<2>(s);   gs += swzxf<2>(gs);
  s += swzxf<4>(s);   gs += swzxf<4>(gs);
  s += swzxf<8>(s);   gs += swzxf<8>(gs);
  s += swzxf<16>(s);  gs += swzxf<16>(gs);

  float logz = (__builtin_amdgcn_logf(s) + LS) * LN2f;
  if (threadIdx.x == 0) out[b] = logz - gs;
}

extern "C" void kernel_launch(void* const* d_in, const int* in_sizes, int n_in,
                              void* d_out, int out_size, void* d_ws, size_t ws_size,
                              hipStream_t stream) {
  const float* emit    = (const float*)d_in[0];
  const float* trans   = (const float*)d_in[1];
  const int*   tags    = (const int*)d_in[2];
  const int*   lengths = (const int*)d_in[3];
  float*       out     = (float*)d_out;
  const int B = in_sizes[3];             // lengths is (B,)
  hipLaunchKernelGGL(crf_fwd, dim3(B), dim3(64), 0, stream,
                     emit, trans, tags, lengths, out, B);
}

// Round 5
// 278.562 us; speedup vs baseline: 1.2107x; 1.0505x over previous
//
#include <hip/hip_runtime.h>

// CRF forward (log-partition minus gold score), B=2048, L=512, T=32.
// BIDIRECTIONAL meet-in-the-middle: the recurrence is linear, so
//   Z = sum_i alpha_m[i] * beta_m[i]   for any meet point m.
// Each block = 128 threads = 2 waves, one batch per block:
//   wave 0: forward  alpha, t = 1..m        (alpha_0 = exp(emit[0]))
//   wave 1: backward beta,  t = len-1..m+1  (beta_{len-1} = 1)
//     beta_{t-1}[i] = sum_j E[i][j] * f_t[j] * beta_t[j]
// This halves the serial chain (R1-R3 all stall-bound at ~650-900 cy/step
// regardless of broadcast transport) and doubles waves/SIMD (2 -> 4) for
// stall hiding. Broadcast via v_readlane -> SGPR (best measured variant).
// Gold score splits by time range: fwd covers t in [0,m], bwd t in [m+1,len).
// Scaled linear space with per-4-step renorm in both directions.
// (Resubmit of R4 source: bench infra failed, no counters returned.)

constexpr int TT = 32;   // tags
constexpr int LL = 512;  // seq len

#define L2E  1.4426950408889634f
#define LN2f 0.6931471805599453f

template<int X>
__device__ __forceinline__ float swzxf(float v) {
  // lane ^ X within each 32-lane group (BitMode: and=0x1F, xor=X)
  return __int_as_float(__builtin_amdgcn_ds_swizzle(__float_as_int(v), (X << 10) | 0x1F));
}
__device__ __forceinline__ float rdlf(float v, int k) {
  // literal k after unroll -> v_readlane_b32 s, v, k
  return __int_as_float(__builtin_amdgcn_readlane(__float_as_int(v), k));
}

// One direction of the recurrence. DIR=0: forward (step s -> time t=1+s,
// a = dot(a)*f_t). DIR=1: backward (step s -> time t=len-1-s, a = dot(a*f_t)).
// Eg: DIR=0 lane j holds E column j (Eg[i]=E[i][j]); DIR=1 lane j holds
// E row j (Eg[k]=E[j][k]).
template<int DIR>
__device__ __forceinline__ void run_dir(
    const float* __restrict__ erow, const int* __restrict__ trow,
    const float* s_trans, const float (&Eg)[TT],
    int j, int ln, int len, int ns,
    float& a, float& gacc, float& LS)
{
  if (ns <= 0) return;
  const int nf = ns >> 3;   // full 8-step chunks
  const int r  = ns & 7;    // tail steps

  float eA[8], eB[8];
  int tvA, tvB;

  // emit element for step s (lane j), clamped (over-reads are unused)
  auto eload = [&](int s) -> float {
    int t = DIR ? (len - 1 - s) : (1 + s);
    t = t > 0 ? t : 0;
    t = t < LL ? t : LL - 1;
    return erow[t * TT + j];
  };
  // tag vector for the chunk at s0. DIR=0: lane k = tags[s0+k]
  // (k -> prev tag, k+1 -> current). DIR=1: lane k = tags[len-1-s0-k]
  // (k -> current tag, k+1 -> prev).
  auto tload = [&](int s0) -> int {
    int ti = DIR ? (len - 1 - s0 - ln) : (s0 + ln);
    ti = ti > 0 ? ti : 0;
    ti = ti < LL ? ti : LL - 1;
    return trow[ti];
  };
  // SGPR-broadcast dot: 32 readlane + 32 fma (4 chains of depth 8)
  auto dot = [&](float x) -> float {
    float c0 = 0.f, c1 = 0.f, c2 = 0.f, c3 = 0.f;
#pragma unroll
    for (int q = 0; q < 8; ++q) {
      c0 = fmaf(rdlf(x, 4 * q + 0), Eg[4 * q + 0], c0);
      c1 = fmaf(rdlf(x, 4 * q + 1), Eg[4 * q + 1], c1);
      c2 = fmaf(rdlf(x, 4 * q + 2), Eg[4 * q + 2], c2);
      c3 = fmaf(rdlf(x, 4 * q + 3), Eg[4 * q + 3], c3);
    }
    return (c0 + c1) + (c2 + c3);
  };
  // renorm by first-lane value (logz-invariant)
  auto renorm = [&]() {
    float mt = fmaxf(a, 1e-30f);
    float m = __int_as_float(__builtin_amdgcn_readfirstlane(__float_as_int(mt)));
    a *= __builtin_amdgcn_rcpf(m);
    LS += __builtin_amdgcn_logf(m);   // v_log_f32 = log2
  };

  // K must be a literal (register indexing)
#define ONESTEP(EC, TVC, K)                                                \
  {                                                                        \
    float F = __builtin_amdgcn_exp2f(EC[K] * L2E);                         \
    int ma = __builtin_amdgcn_readlane(TVC, DIR ? (K) : (K) + 1);          \
    int pv = __builtin_amdgcn_readlane(TVC, DIR ? (K) + 1 : (K));          \
    float tr = s_trans[(pv << 5) + j];                                     \
    if (DIR) a = dot(a * F); else a = dot(a) * F;                          \
    gacc += (j == ma) ? (EC[K] + tr) : 0.f;                                \
  }

#define CHUNK(EC, TVC, EN, TVN, S0)                                        \
  {                                                                        \
    _Pragma("unroll")                                                      \
    for (int k = 0; k < 8; ++k) EN[k] = eload((S0) + 8 + k);               \
    TVN = tload((S0) + 8);                                                 \
    ONESTEP(EC, TVC, 0) ONESTEP(EC, TVC, 1)                                \
    ONESTEP(EC, TVC, 2) ONESTEP(EC, TVC, 3)                                \
    renorm();                                                              \
    ONESTEP(EC, TVC, 4) ONESTEP(EC, TVC, 5)                                \
    ONESTEP(EC, TVC, 6) ONESTEP(EC, TVC, 7)                                \
    renorm();                                                              \
  }

  // fill chunk 0
#pragma unroll
  for (int k = 0; k < 8; ++k) eA[k] = eload(k);
  tvA = tload(0);

  int c = 0;
  for (; c + 2 <= nf; c += 2) {
    CHUNK(eA, tvA, eB, tvB, (c + 0) << 3);
    CHUNK(eB, tvB, eA, tvA, (c + 1) << 3);
  }
  if (c < nf) {
    CHUNK(eA, tvA, eB, tvB, c << 3);
    ++c;
  }

  // tail: r in 0..7 steps, data in buffer (nf&1 ? B : A)
#define TAIL(EC, TVC)                                                      \
  {                                                                        \
    if (0 < r) ONESTEP(EC, TVC, 0)                                         \
    if (1 < r) ONESTEP(EC, TVC, 1)                                         \
    if (2 < r) ONESTEP(EC, TVC, 2)                                         \
    if (3 < r) { ONESTEP(EC, TVC, 3) renorm(); }                           \
    if (4 < r) ONESTEP(EC, TVC, 4)                                         \
    if (5 < r) ONESTEP(EC, TVC, 5)                                         \
    if (6 < r) ONESTEP(EC, TVC, 6)                                         \
  }

  if (nf & 1) TAIL(eB, tvB) else TAIL(eA, tvA)

#undef ONESTEP
#undef CHUNK
#undef TAIL
}

__global__ __launch_bounds__(128, 4) void crf_fwd(
    const float* __restrict__ emit, const float* __restrict__ trans,
    const int* __restrict__ tags, const int* __restrict__ lengths,
    float* __restrict__ out, int B)
{
  __shared__ float s_trans[TT * TT];
  __shared__ float s_vec[2][TT];
  __shared__ float s_scl[2][2];
  {
    // 128 threads x 2 float4 = 1024 floats
    const float4* t4 = (const float4*)trans;
    float4* st4 = (float4*)s_trans;
    st4[threadIdx.x]       = t4[threadIdx.x];
    st4[threadIdx.x + 128] = t4[threadIdx.x + 128];
  }
  __syncthreads();

  const int j  = threadIdx.x & 31;  // tag index (both wave halves identical)
  const int ln = threadIdx.x & 63;  // lane within wave
  const int wv = threadIdx.x >> 6;  // 0 = forward wave, 1 = backward wave
  const int b  = blockIdx.x;        // one batch per block

  // E in registers: fwd lane j holds column j; bwd lane j holds row j.
  float Eg[TT];
#pragma unroll
  for (int i = 0; i < TT; ++i) {
    int idx = wv ? (j * TT + i) : (i * TT + j);
    Eg[i] = __builtin_amdgcn_exp2f(s_trans[idx] * L2E);
  }
#pragma unroll
  for (int i = 0; i < TT; ++i) asm volatile("" : "+v"(Eg[i]));

  const int len = lengths[b];       // wave-uniform
  const int m   = (len - 1) >> 1;   // meet point
  const int ns  = wv ? (len - 1 - m) : m;   // serial steps for this wave
  const float* erow = emit + (size_t)b * (LL * TT);
  const int*   trow = tags + (size_t)b * LL;

  float a, gacc, LS = 0.f;
  if (wv == 0) {
    float e0 = erow[j];
    int   t0 = trow[0];
    a    = __builtin_amdgcn_exp2f(e0 * L2E);   // alpha_0
    gacc = (j == t0) ? e0 : 0.f;               // gold emit at t=0
  } else {
    a    = 1.f;                                // beta_{len-1}
    gacc = 0.f;
  }

  if (wv == 0)
    run_dir<0>(erow, trow, s_trans, Eg, j, ln, len, ns, a, gacc, LS);
  else
    run_dir<1>(erow, trow, s_trans, Eg, j, ln, len, ns, a, gacc, LS);

  // reduce gold within the wave's 32-lane groups
  float gs = gacc;
  gs += swzxf<1>(gs);  gs += swzxf<2>(gs);  gs += swzxf<4>(gs);
  gs += swzxf<8>(gs);  gs += swzxf<16>(gs);

  // publish meet state
  s_vec[wv][j] = a;                 // lanes j and j+32 write same value
  if (ln == 0) { s_scl[wv][0] = gs; s_scl[wv][1] = LS; }
  __syncthreads();

  if (wv == 0) {
    // Z * 2^-(LSf+LSb) = sum_i alpha_m[i] * beta_m[i]
    float p = s_vec[0][j] * s_vec[1][j];
    p += swzxf<1>(p);  p += swzxf<2>(p);  p += swzxf<4>(p);
    p += swzxf<8>(p);  p += swzxf<16>(p);
    float logz = (__builtin_amdgcn_logf(p) + s_scl[0][1] + s_scl[1][1]) * LN2f;
    if (threadIdx.x == 0) out[b] = logz - (s_scl[0][0] + s_scl[1][0]);
  }
}

extern "C" void kernel_launch(void* const* d_in, const int* in_sizes, int n_in,
                              void* d_out, int out_size, void* d_ws, size_t ws_size,
                              hipStream_t stream) {
  const float* emit    = (const float*)d_in[0];
  const float* trans   = (const float*)d_in[1];
  const int*   tags    = (const int*)d_in[2];
  const int*   lengths = (const int*)d_in[3];
  float*       out     = (float*)d_out;
  const int B = in_sizes[3];             // lengths is (B,)
  hipLaunchKernelGGL(crf_fwd, dim3(B), dim3(128), 0, stream,
                     emit, trans, tags, lengths, out, B);
}